// Round 1
// baseline (78794.330 us; speedup 1.0000x reference)
//
#include <hip/hip_runtime.h>
#include <hip/hip_bf16.h>

#define B_  512
#define D_  1024
#define E_  4
#define L_  2
#define FF_ 4096
#define ND_ 3
#define BT_ 1536   // ND_*B_
#define STEPS_ 5
#define H_ 8

static __device__ __forceinline__ float gelu_f(float x) {
    return 0.5f * x * (1.0f + erff(x * 0.70710678118654752f));
}

// C[M,N] = act(A[M,K] @ W[N,K]^T + bias[N]) (+ R[M,N] if R!=null)
// Requires: M%64==0, N%64==0, K%16==0. act: 0=none, 1=exact GELU.
__global__ __launch_bounds__(256) void gemm_f32(
    const float* __restrict__ A, const float* __restrict__ W,
    const float* __restrict__ bias, const float* __restrict__ R,
    float* __restrict__ C, int M, int N, int K, int act)
{
    __shared__ float As[16][68];
    __shared__ float Bs[16][68];
    const int tid = threadIdx.x;
    const int tx = tid & 15;        // N direction
    const int ty = tid >> 4;        // M direction
    const long row0 = (long)blockIdx.y * 64;
    const long col0 = (long)blockIdx.x * 64;
    const int lr = tid >> 2;        // loader row in tile [0,64)
    const int lq = (tid & 3) << 2;  // loader k offset {0,4,8,12}
    const float* Ap = A + (row0 + lr) * (long)K + lq;
    const float* Wp = W + (col0 + lr) * (long)K + lq;
    float acc[4][4] = {};
    for (int k0 = 0; k0 < K; k0 += 16) {
        const float4 av = *(const float4*)(Ap + k0);
        const float4 wv = *(const float4*)(Wp + k0);
        __syncthreads();
        As[lq + 0][lr] = av.x; As[lq + 1][lr] = av.y;
        As[lq + 2][lr] = av.z; As[lq + 3][lr] = av.w;
        Bs[lq + 0][lr] = wv.x; Bs[lq + 1][lr] = wv.y;
        Bs[lq + 2][lr] = wv.z; Bs[lq + 3][lr] = wv.w;
        __syncthreads();
        #pragma unroll
        for (int kk = 0; kk < 16; ++kk) {
            const float4 a4 = *(const float4*)&As[kk][ty << 2];
            const float4 b4 = *(const float4*)&Bs[kk][tx << 2];
            const float aa[4] = {a4.x, a4.y, a4.z, a4.w};
            const float bb[4] = {b4.x, b4.y, b4.z, b4.w};
            #pragma unroll
            for (int i = 0; i < 4; ++i)
                #pragma unroll
                for (int j = 0; j < 4; ++j)
                    acc[i][j] = fmaf(aa[i], bb[j], acc[i][j]);
        }
    }
    const float4 bv = *(const float4*)(bias + col0 + (tx << 2));
    const float bb[4] = {bv.x, bv.y, bv.z, bv.w};
    #pragma unroll
    for (int i = 0; i < 4; ++i) {
        const long row = row0 + (ty << 2) + i;
        const long off = row * (long)N + col0 + (tx << 2);
        float o[4];
        #pragma unroll
        for (int j = 0; j < 4; ++j) {
            o[j] = acc[i][j] + bb[j];
            if (act) o[j] = gelu_f(o[j]);
        }
        if (R) {
            const float4 rv = *(const float4*)(R + off);
            o[0] += rv.x; o[1] += rv.y; o[2] += rv.z; o[3] += rv.w;
        }
        *(float4*)(C + off) = make_float4(o[0], o[1], o[2], o[3]);
    }
}

// One block per row of length 1024. Y is compact (stride 1024). act: 0/1(GELU).
__global__ __launch_bounds__(256) void ln_kernel(
    const float* __restrict__ X, long xstride,
    const float* __restrict__ gamma, const float* __restrict__ beta,
    float* __restrict__ Y, int act)
{
    const long r = blockIdx.x;
    const int tid = threadIdx.x;
    __shared__ float red[8];
    const float4 v = *(const float4*)(X + r * xstride + (tid << 2));
    float s = v.x + v.y + v.z + v.w;
    #pragma unroll
    for (int off = 32; off; off >>= 1) s += __shfl_xor(s, off);
    if ((tid & 63) == 0) red[tid >> 6] = s;
    __syncthreads();
    const float mean = (red[0] + red[1] + red[2] + red[3]) * (1.0f / 1024.0f);
    const float dx = v.x - mean, dy = v.y - mean, dz = v.z - mean, dw = v.w - mean;
    float s2 = dx * dx + dy * dy + dz * dz + dw * dw;
    #pragma unroll
    for (int off = 32; off; off >>= 1) s2 += __shfl_xor(s2, off);
    if ((tid & 63) == 0) red[4 + (tid >> 6)] = s2;
    __syncthreads();
    const float var = (red[4] + red[5] + red[6] + red[7]) * (1.0f / 1024.0f);
    const float inv = rsqrtf(var + 1e-5f);
    const float4 g = *(const float4*)(gamma + (tid << 2));
    const float4 b = *(const float4*)(beta + (tid << 2));
    float o0 = dx * inv * g.x + b.x;
    float o1 = dy * inv * g.y + b.y;
    float o2 = dz * inv * g.z + b.z;
    float o3 = dw * inv * g.w + b.w;
    if (act) { o0 = gelu_f(o0); o1 = gelu_f(o1); o2 = gelu_f(o2); o3 = gelu_f(o3); }
    *(float4*)(Y + (r << 10) + (tid << 2)) = make_float4(o0, o1, o2, o3);
}

// One wave per (batch-row i, head h, query tq). qkv: (BT_*T, 3072); o: (BT_*T, 1024)
template<int TT>
__global__ __launch_bounds__(256) void attn_kernel(
    const float* __restrict__ qkv, float* __restrict__ o)
{
    const int item = (int)(((long)blockIdx.x * 256 + threadIdx.x) >> 6);
    const int lane = threadIdx.x & 63;
    const int tq = item % TT;
    const int h  = (item / TT) & 7;
    const int i  = item / (TT * 8);
    const float* base = qkv + (long)i * TT * 3072;
    const float* q = base + (long)tq * 3072 + h * 128;
    const float q0 = q[lane], q1 = q[lane + 64];
    float s[TT];
    const float scale = 0.088388347648318447f;  // 1/sqrt(128)
    #pragma unroll
    for (int tk = 0; tk < TT; ++tk) {
        const float* k = base + (long)tk * 3072 + 1024 + h * 128;
        float p = q0 * k[lane] + q1 * k[lane + 64];
        #pragma unroll
        for (int off = 32; off; off >>= 1) p += __shfl_xor(p, off);
        s[tk] = p * scale;
    }
    float m = s[0];
    #pragma unroll
    for (int tk = 1; tk < TT; ++tk) m = fmaxf(m, s[tk]);
    float den = 0.f;
    #pragma unroll
    for (int tk = 0; tk < TT; ++tk) { s[tk] = expf(s[tk] - m); den += s[tk]; }
    float o0 = 0.f, o1 = 0.f;
    #pragma unroll
    for (int tk = 0; tk < TT; ++tk) {
        const float* v = base + (long)tk * 3072 + 2048 + h * 128;
        o0 += s[tk] * v[lane]; o1 += s[tk] * v[lane + 64];
    }
    const float id = 1.0f / den;
    float* op = o + ((long)i * TT + tq) * 1024 + h * 128;
    op[lane] = o0 * id; op[lane + 64] = o1 * id;
}

// One wave per batch row: logits (4) + top-2 + softmax -> weights (B,4)
__global__ __launch_bounds__(256) void gate_kernel(
    const float* __restrict__ g, const float* __restrict__ gw2,
    const float* __restrict__ gb2, float* __restrict__ wout)
{
    const int b = (int)(((long)blockIdx.x * 256 + threadIdx.x) >> 6);
    const int lane = threadIdx.x & 63;
    float acc[E_] = {};
    const float* row = g + (long)b * 1024;
    for (int d = lane; d < 1024; d += 64) {
        const float x = row[d];
        #pragma unroll
        for (int j = 0; j < E_; ++j) acc[j] += x * gw2[j * 1024 + d];
    }
    #pragma unroll
    for (int j = 0; j < E_; ++j) {
        #pragma unroll
        for (int off = 32; off; off >>= 1) acc[j] += __shfl_xor(acc[j], off);
        acc[j] += gb2[j];
    }
    // top-2 with jax.lax.top_k tie semantics (earliest index wins via strict >)
    int i0 = 0; float v0 = acc[0];
    #pragma unroll
    for (int j = 1; j < E_; ++j) if (acc[j] > v0) { v0 = acc[j]; i0 = j; }
    int i1 = -1; float v1 = -1e30f;
    #pragma unroll
    for (int j = 0; j < E_; ++j) if (j != i0 && acc[j] > v1) { v1 = acc[j]; i1 = j; }
    const float p1 = expf(v1 - v0);
    const float den = 1.0f + p1;
    const float g0 = 1.0f / den, g1 = p1 / den;
    if (lane < E_) wout[b * E_ + lane] = (lane == i0) ? g0 : (lane == i1) ? g1 : 0.0f;
}

__global__ __launch_bounds__(256) void build_flat_kernel(
    const float* __restrict__ w, const float* __restrict__ a,
    const float* __restrict__ r, float* __restrict__ flat)
{
    const long e4 = ((long)blockIdx.x * 256 + threadIdx.x) << 2;  // < B_*3072
    const int b = (int)(e4 / 3072);
    const int cd = (int)(e4 % 3072);
    const int c = cd >> 10, d = cd & 1023;
    const float* src = (c == 0) ? w : (c == 1) ? a : r;
    *(float4*)(flat + e4) = *(const float4*)(src + ((long)b << 10) + d);
}

__global__ __launch_bounds__(256) void build_big_kernel(
    const float* __restrict__ w, const float* __restrict__ a,
    const float* __restrict__ r, const float* __restrict__ doff,
    float* __restrict__ big)
{
    const long e4 = ((long)blockIdx.x * 256 + threadIdx.x) << 2;  // < BT_*3072
    const int i = (int)(e4 / 3072);           // n*B_ + b
    const int cd = (int)(e4 % 3072);
    const int c = cd >> 10, d = cd & 1023;
    const int n = i / B_, b = i & (B_ - 1);
    const float* src = (c == 0) ? w : (c == 1) ? a : r;
    const float4 x = *(const float4*)(src + ((long)b << 10) + d);
    const float4 oo = *(const float4*)(doff + ((long)(n * 3 + c) << 10) + d);
    *(float4*)(big + e4) = make_float4(x.x + oo.x, x.y + oo.y, x.z + oo.z, x.w + oo.w);
}

// mean over 3 chunks of 1024: dst[i,d] = (src[i,d] + src[i,1024+d] + src[i,2048+d])/3
__global__ __launch_bounds__(256) void mean3_kernel(
    const float* __restrict__ src, float* __restrict__ dst)
{
    const long idx = (long)blockIdx.x * 256 + threadIdx.x;  // rows*256
    const long i = idx >> 8;
    const int d4 = (int)(idx & 255) << 2;
    const float* p = src + i * 3072 + d4;
    const float4 x = *(const float4*)p;
    const float4 y = *(const float4*)(p + 1024);
    const float4 z = *(const float4*)(p + 2048);
    const float c = 1.0f / 3.0f;
    *(float4*)(dst + (i << 10) + d4) = make_float4(
        (x.x + y.x + z.x) * c, (x.y + y.y + z.y) * c,
        (x.z + y.z + z.z) * c, (x.w + y.w + z.w) * c);
}

__global__ __launch_bounds__(256) void build_st_kernel(
    const float* __restrict__ seq, const float* __restrict__ pos_e,
    float* __restrict__ st, int T)
{
    const long idx = (long)blockIdx.x * 256 + threadIdx.x;  // BT_*T*256
    const long row = idx >> 8;          // i*T + tau
    const int d4 = (int)(idx & 255) << 2;
    const int tau = (int)(row % T);
    const long i = row / T;
    const float4 s = *(const float4*)(seq + (((long)tau * BT_ + i) << 10) + d4);
    const float4 p = *(const float4*)(pos_e + ((long)tau << 10) + d4);
    *(float4*)(st + (row << 10) + d4) = make_float4(s.x + p.x, s.y + p.y, s.z + p.z, s.w + p.w);
}

// out[n,s,c,b,d] (+)= wbuf[b,e] * tp[(s*BT_ + n*B_ + b), c*1024 + d]
__global__ __launch_bounds__(256) void combine_kernel(
    const float* __restrict__ tp, const float* __restrict__ wbuf,
    float* __restrict__ out, int e)
{
    const long idx = (long)blockIdx.x * 256 + threadIdx.x;  // STEPS_*BT_*3072/4
    const long e4 = idx << 2;
    const long row = e4 / 3072;          // s*BT_ + i
    const int cd = (int)(e4 % 3072);
    const int c = cd >> 10, d = cd & 1023;
    const int s = (int)(row / BT_);
    const int i = (int)(row % BT_);
    const int n = i / B_, b = i & (B_ - 1);
    const float wgt = wbuf[b * E_ + e];
    const float4 t = *(const float4*)(tp + e4);
    const long off = ((((long)(n * STEPS_ + s) * 3 + c) * B_ + b) << 10) + d;
    float4 o = make_float4(wgt * t.x, wgt * t.y, wgt * t.z, wgt * t.w);
    if (e != 0) {
        const float4 p = *(const float4*)(out + off);
        o.x += p.x; o.y += p.y; o.z += p.z; o.w += p.w;
    }
    *(float4*)(out + off) = o;
}

extern "C" void kernel_launch(void* const* d_in, const int* in_sizes, int n_in,
                              void* d_out, int out_size, void* d_ws, size_t ws_size,
                              hipStream_t stream)
{
    const float* iw   = (const float*)d_in[0];
    const float* ia   = (const float*)d_in[1];
    const float* ir   = (const float*)d_in[2];
    const float* doff = (const float*)d_in[3];
    const float* gw1  = (const float*)d_in[4];
    const float* gb1  = (const float*)d_in[5];
    const float* glnw = (const float*)d_in[6];
    const float* glnb = (const float*)d_in[7];
    const float* gw2  = (const float*)d_in[8];
    const float* gb2  = (const float*)d_in[9];
    const float* pos  = (const float*)d_in[10];
    const float* anw  = (const float*)d_in[11];
    const float* anb  = (const float*)d_in[12];
    const float* inw  = (const float*)d_in[13];
    const float* inb  = (const float*)d_in[14];
    const float* oww  = (const float*)d_in[15];
    const float* owb  = (const float*)d_in[16];
    const float* fnw  = (const float*)d_in[17];
    const float* fnb  = (const float*)d_in[18];
    const float* w1   = (const float*)d_in[19];
    const float* b1   = (const float*)d_in[20];
    const float* w2   = (const float*)d_in[21];
    const float* b2   = (const float*)d_in[22];
    const float* tlnw = (const float*)d_in[23];
    const float* tlnb = (const float*)d_in[24];
    const float* tw1  = (const float*)d_in[25];
    const float* tb1  = (const float*)d_in[26];
    const float* tw2  = (const float*)d_in[27];
    const float* tb2  = (const float*)d_in[28];
    float* out = (float*)d_out;

    float* ws    = (float*)d_ws;
    float* wbuf  = ws;                          // B_*4          = 2048
    float* flatb = wbuf + 2048;                 // B_*3072
    float* glin  = flatb + (long)B_ * 3072;     // B_*1024
    float* big   = glin + (long)B_ * 1024;      // BT_*3072
    float* seq   = big + (long)BT_ * 3072;      // 6*BT_*1024
    float* st    = seq + 6L * BT_ * 1024;       // 5*BT_*1024
    float* xn    = st + 5L * BT_ * 1024;        // 5*BT_*1024   (also attn-out / compact-LN buf)
    float* qkvb  = xn + 5L * BT_ * 1024;        // 5*BT_*3072   (also triplet-proj output)
    float* ffh   = qkvb + 5L * BT_ * 3072;      // 5*BT_*4096   (also triplet-proj hidden)
    if (ws_size < 87033856UL * sizeof(float)) return;  // 348 MB needed

    // ---- gating (always f32; expert selection must be bit-stable) ----
    build_flat_kernel<<<B_ * 3, 256, 0, stream>>>(iw, ia, ir, flatb);
    gemm_f32<<<dim3(1024 / 64, B_ / 64), 256, 0, stream>>>(
        flatb, gw1, gb1, nullptr, glin, B_, 1024, 3072, 0);
    ln_kernel<<<B_, 256, 0, stream>>>(glin, 1024, glnw, glnb, glin, 1);
    gate_kernel<<<B_ / 4, 256, 0, stream>>>(glin, gw2, gb2, wbuf);

    // ---- diversified starts ----
    build_big_kernel<<<BT_ * 3, 256, 0, stream>>>(iw, ia, ir, doff, big);
    mean3_kernel<<<BT_, 256, 0, stream>>>(big, seq);  // seq[0] = mean over triplet

    for (int e = 0; e < E_; ++e) {
        const float* pos_e = pos + (long)e * 10 * 1024;
        for (int t = 0; t < STEPS_; ++t) {
            const int T = t + 1;
            const int MT = BT_ * T;
            build_st_kernel<<<MT, 256, 0, stream>>>(seq, pos_e, st, T);
            for (int l = 0; l < L_; ++l) {
                const long wi = (long)e * L_ + l;
                ln_kernel<<<MT, 256, 0, stream>>>(st, 1024, anw + wi * 1024, anb + wi * 1024, xn, 0);
                gemm_f32<<<dim3(3072 / 64, MT / 64), 256, 0, stream>>>(
                    xn, inw + wi * 3072 * 1024, inb + wi * 3072, nullptr, qkvb, MT, 3072, 1024, 0);
                switch (T) {
                    case 1: attn_kernel<1><<<BT_ * H_ * 1 / 4, 256, 0, stream>>>(qkvb, xn); break;
                    case 2: attn_kernel<2><<<BT_ * H_ * 2 / 4, 256, 0, stream>>>(qkvb, xn); break;
                    case 3: attn_kernel<3><<<BT_ * H_ * 3 / 4, 256, 0, stream>>>(qkvb, xn); break;
                    case 4: attn_kernel<4><<<BT_ * H_ * 4 / 4, 256, 0, stream>>>(qkvb, xn); break;
                    case 5: attn_kernel<5><<<BT_ * H_ * 5 / 4, 256, 0, stream>>>(qkvb, xn); break;
                }
                gemm_f32<<<dim3(1024 / 64, MT / 64), 256, 0, stream>>>(
                    xn, oww + wi * 1024 * 1024, owb + wi * 1024, st, st, MT, 1024, 1024, 0);
                ln_kernel<<<MT, 256, 0, stream>>>(st, 1024, fnw + wi * 1024, fnb + wi * 1024, xn, 0);
                gemm_f32<<<dim3(4096 / 64, MT / 64), 256, 0, stream>>>(
                    xn, w1 + wi * 4096 * 1024, b1 + wi * 4096, nullptr, ffh, MT, 4096, 1024, 1);
                gemm_f32<<<dim3(1024 / 64, MT / 64), 256, 0, stream>>>(
                    ffh, w2 + wi * 1024 * 4096, b2 + wi * 1024, st, st, MT, 1024, 4096, 0);
            }
            // triplet projection of last token -> next seq entry
            ln_kernel<<<BT_, 256, 0, stream>>>(st + (long)t * 1024, (long)T * 1024,
                                               tlnw + (long)e * 1024, tlnb + (long)e * 1024, xn, 0);
            gemm_f32<<<dim3(2048 / 64, BT_ / 64), 256, 0, stream>>>(
                xn, tw1 + (long)e * 2048 * 1024, tb1 + (long)e * 2048, nullptr, ffh, BT_, 2048, 1024, 1);
            gemm_f32<<<dim3(3072 / 64, BT_ / 64), 256, 0, stream>>>(
                ffh, tw2 + (long)e * 3072 * 2048, tb2 + (long)e * 3072, nullptr, qkvb, BT_, 3072, 2048, 0);
            mean3_kernel<<<BT_, 256, 0, stream>>>(qkvb, seq + (long)(t + 1) * BT_ * 1024);
        }
        // final triplet projection over embs = seq[1..5] (contiguous 5*BT_ rows)
        ln_kernel<<<STEPS_ * BT_, 256, 0, stream>>>(seq + (long)BT_ * 1024, 1024,
                                                    tlnw + (long)e * 1024, tlnb + (long)e * 1024, xn, 0);
        gemm_f32<<<dim3(2048 / 64, STEPS_ * BT_ / 64), 256, 0, stream>>>(
            xn, tw1 + (long)e * 2048 * 1024, tb1 + (long)e * 2048, nullptr, ffh, STEPS_ * BT_, 2048, 1024, 1);
        gemm_f32<<<dim3(3072 / 64, STEPS_ * BT_ / 64), 256, 0, stream>>>(
            ffh, tw2 + (long)e * 3072 * 2048, tb2 + (long)e * 3072, nullptr, qkvb, STEPS_ * BT_, 3072, 2048, 0);
        combine_kernel<<<STEPS_ * BT_ * 3, 256, 0, stream>>>(qkvb, wbuf, out, e);
    }
}

// Round 2
// 16857.951 us; speedup vs baseline: 4.6740x; 4.6740x over previous
//
#include <hip/hip_runtime.h>
#include <hip/hip_bf16.h>
#include <cstdint>

#define B_  512
#define D_  1024
#define E_  4
#define L_  2
#define FF_ 4096
#define ND_ 3
#define BT_ 1536   // ND_*B_
#define STEPS_ 5
#define H_ 8

typedef __attribute__((ext_vector_type(8))) __bf16 bf16x8;
typedef __attribute__((ext_vector_type(4))) float f32x4;

static __device__ __forceinline__ float gelu_f(float x) {
    return 0.5f * x * (1.0f + erff(x * 0.70710678118654752f));
}

static __device__ __forceinline__ unsigned short f2bf(float x) {
    unsigned u = __builtin_bit_cast(unsigned, x);
    u = (u + 0x7fff + ((u >> 16) & 1)) >> 16;   // RNE
    return (unsigned short)u;
}

static __device__ __forceinline__ void gload16(const void* g, void* l) {
    __builtin_amdgcn_global_load_lds(
        (const __attribute__((address_space(1))) unsigned int*)g,
        (__attribute__((address_space(3))) unsigned int*)l, 16, 0, 0);
}

// ---------------- bf16 MFMA GEMM (m97 structure) ----------------
// C[M,N] = act(A[M,K] @ W[N,K]^T + bias) (+R). A,W bf16 (K-contig), bias/R f32.
// M%128==0, N%128==0, K%32==0. ACT: 0/1 gelu. OUTBF: 0 -> f32 C, 1 -> bf16 C.
template<int ACT, int OUTBF>
__global__ __launch_bounds__(256) void gemm_bf16(
    const unsigned short* __restrict__ A, const unsigned short* __restrict__ W,
    const float* __restrict__ bias, const float* __restrict__ R,
    void* __restrict__ Cout, int N, int K)
{
    __shared__ __align__(16) unsigned short As[128 * 32];
    __shared__ __align__(16) unsigned short Bs[128 * 32];
    const int t = threadIdx.x;
    const int lane = t & 63;
    const int wid = t >> 6;
    const int wr = wid >> 1, wc = wid & 1;
    const long row0 = (long)blockIdx.y * 128;
    const long col0 = (long)blockIdx.x * 128;
    const int l15 = lane & 15, l4 = lane >> 4;
    const int ebase = wid << 6;               // wave-uniform

    f32x4 acc[4][4] = {};

    const int e0 = t, e1 = t + 256;
    const unsigned short* Ag0 = A + (row0 + (e0 >> 2)) * (long)K + (e0 & 3) * 8;
    const unsigned short* Ag1 = A + (row0 + (e1 >> 2)) * (long)K + (e1 & 3) * 8;
    const unsigned short* Wg0 = W + (col0 + (e0 >> 2)) * (long)K + (e0 & 3) * 8;
    const unsigned short* Wg1 = W + (col0 + (e1 >> 2)) * (long)K + (e1 & 3) * 8;
    char* Ad0 = (char*)As + ebase * 16;
    char* Ad1 = (char*)As + (256 + ebase) * 16;
    char* Bd0 = (char*)Bs + ebase * 16;
    char* Bd1 = (char*)Bs + (256 + ebase) * 16;

    for (int k0 = 0; k0 < K; k0 += 32) {
        __syncthreads();
        gload16(Ag0 + k0, Ad0);
        gload16(Ag1 + k0, Ad1);
        gload16(Wg0 + k0, Bd0);
        gload16(Wg1 + k0, Bd1);
        __syncthreads();
        bf16x8 a[4], b[4];
        #pragma unroll
        for (int m = 0; m < 4; ++m)
            a[m] = *(const bf16x8*)((const char*)As + (wr * 64 + m * 16 + l15) * 64 + l4 * 16);
        #pragma unroll
        for (int n = 0; n < 4; ++n)
            b[n] = *(const bf16x8*)((const char*)Bs + (wc * 64 + n * 16 + l15) * 64 + l4 * 16);
        #pragma unroll
        for (int m = 0; m < 4; ++m)
            #pragma unroll
            for (int n = 0; n < 4; ++n)
                acc[m][n] = __builtin_amdgcn_mfma_f32_16x16x32_bf16(a[m], b[n], acc[m][n], 0, 0, 0);
    }

    #pragma unroll
    for (int n = 0; n < 4; ++n) {
        const long col = col0 + wc * 64 + n * 16 + l15;
        const float bn = bias[col];
        #pragma unroll
        for (int m = 0; m < 4; ++m) {
            const long rbase = row0 + wr * 64 + m * 16 + l4 * 4;
            #pragma unroll
            for (int r = 0; r < 4; ++r) {
                float o = acc[m][n][r] + bn;
                if (ACT) o = gelu_f(o);
                const long off = (rbase + r) * (long)N + col;
                if (R) o += R[off];
                if (OUTBF) ((unsigned short*)Cout)[off] = f2bf(o);
                else       ((float*)Cout)[off] = o;
            }
        }
    }
}

// ---------------- f32 GEMM (gating only — bit-stable expert pick) ----------------
__global__ __launch_bounds__(256) void gemm_f32(
    const float* __restrict__ A, const float* __restrict__ W,
    const float* __restrict__ bias, const float* __restrict__ R,
    float* __restrict__ C, int M, int N, int K, int act)
{
    __shared__ float As[16][68];
    __shared__ float Bs[16][68];
    const int tid = threadIdx.x;
    const int tx = tid & 15;
    const int ty = tid >> 4;
    const long row0 = (long)blockIdx.y * 64;
    const long col0 = (long)blockIdx.x * 64;
    const int lr = tid >> 2;
    const int lq = (tid & 3) << 2;
    const float* Ap = A + (row0 + lr) * (long)K + lq;
    const float* Wp = W + (col0 + lr) * (long)K + lq;
    float acc[4][4] = {};
    for (int k0 = 0; k0 < K; k0 += 16) {
        const float4 av = *(const float4*)(Ap + k0);
        const float4 wv = *(const float4*)(Wp + k0);
        __syncthreads();
        As[lq + 0][lr] = av.x; As[lq + 1][lr] = av.y;
        As[lq + 2][lr] = av.z; As[lq + 3][lr] = av.w;
        Bs[lq + 0][lr] = wv.x; Bs[lq + 1][lr] = wv.y;
        Bs[lq + 2][lr] = wv.z; Bs[lq + 3][lr] = wv.w;
        __syncthreads();
        #pragma unroll
        for (int kk = 0; kk < 16; ++kk) {
            const float4 a4 = *(const float4*)&As[kk][ty << 2];
            const float4 b4 = *(const float4*)&Bs[kk][tx << 2];
            const float aa[4] = {a4.x, a4.y, a4.z, a4.w};
            const float bb[4] = {b4.x, b4.y, b4.z, b4.w};
            #pragma unroll
            for (int i = 0; i < 4; ++i)
                #pragma unroll
                for (int j = 0; j < 4; ++j)
                    acc[i][j] = fmaf(aa[i], bb[j], acc[i][j]);
        }
    }
    const float4 bv = *(const float4*)(bias + col0 + (tx << 2));
    const float bb[4] = {bv.x, bv.y, bv.z, bv.w};
    #pragma unroll
    for (int i = 0; i < 4; ++i) {
        const long row = row0 + (ty << 2) + i;
        const long off = row * (long)N + col0 + (tx << 2);
        float o[4];
        #pragma unroll
        for (int j = 0; j < 4; ++j) {
            o[j] = acc[i][j] + bb[j];
            if (act) o[j] = gelu_f(o[j]);
        }
        if (R) {
            const float4 rv = *(const float4*)(R + off);
            o[0] += rv.x; o[1] += rv.y; o[2] += rv.z; o[3] += rv.w;
        }
        *(float4*)(C + off) = make_float4(o[0], o[1], o[2], o[3]);
    }
}

// ---------------- LayerNorm: f32 in, f32 or bf16 out ----------------
template<int ACT, int OUTBF>
__global__ __launch_bounds__(256) void ln_kernel(
    const float* __restrict__ X, long xstride,
    const float* __restrict__ gamma, const float* __restrict__ beta,
    void* __restrict__ Y)
{
    const long r = blockIdx.x;
    const int tid = threadIdx.x;
    __shared__ float red[8];
    const float4 v = *(const float4*)(X + r * xstride + (tid << 2));
    float s = v.x + v.y + v.z + v.w;
    #pragma unroll
    for (int off = 32; off; off >>= 1) s += __shfl_xor(s, off);
    if ((tid & 63) == 0) red[tid >> 6] = s;
    __syncthreads();
    const float mean = (red[0] + red[1] + red[2] + red[3]) * (1.0f / 1024.0f);
    const float dx = v.x - mean, dy = v.y - mean, dz = v.z - mean, dw = v.w - mean;
    float s2 = dx * dx + dy * dy + dz * dz + dw * dw;
    #pragma unroll
    for (int off = 32; off; off >>= 1) s2 += __shfl_xor(s2, off);
    if ((tid & 63) == 0) red[4 + (tid >> 6)] = s2;
    __syncthreads();
    const float var = (red[4] + red[5] + red[6] + red[7]) * (1.0f / 1024.0f);
    const float inv = rsqrtf(var + 1e-5f);
    const float4 g = *(const float4*)(gamma + (tid << 2));
    const float4 b = *(const float4*)(beta + (tid << 2));
    float o0 = dx * inv * g.x + b.x;
    float o1 = dy * inv * g.y + b.y;
    float o2 = dz * inv * g.z + b.z;
    float o3 = dw * inv * g.w + b.w;
    if (ACT) { o0 = gelu_f(o0); o1 = gelu_f(o1); o2 = gelu_f(o2); o3 = gelu_f(o3); }
    if (OUTBF) {
        ushort4 o = make_ushort4(f2bf(o0), f2bf(o1), f2bf(o2), f2bf(o3));
        *(ushort4*)((unsigned short*)Y + (r << 10) + (tid << 2)) = o;
    } else {
        *(float4*)((float*)Y + (r << 10) + (tid << 2)) = make_float4(o0, o1, o2, o3);
    }
}

// ---------------- attention: f32 qkv in, bf16 out ----------------
template<int TT>
__global__ __launch_bounds__(256) void attn_kernel(
    const float* __restrict__ qkv, unsigned short* __restrict__ o)
{
    const int item = (int)(((long)blockIdx.x * 256 + threadIdx.x) >> 6);
    const int lane = threadIdx.x & 63;
    const int tq = item % TT;
    const int h  = (item / TT) & 7;
    const int i  = item / (TT * 8);
    const float* base = qkv + (long)i * TT * 3072;
    const float* q = base + (long)tq * 3072 + h * 128;
    const float q0 = q[lane], q1 = q[lane + 64];
    float s[TT];
    const float scale = 0.088388347648318447f;  // 1/sqrt(128)
    #pragma unroll
    for (int tk = 0; tk < TT; ++tk) {
        const float* k = base + (long)tk * 3072 + 1024 + h * 128;
        float p = q0 * k[lane] + q1 * k[lane + 64];
        #pragma unroll
        for (int off = 32; off; off >>= 1) p += __shfl_xor(p, off);
        s[tk] = p * scale;
    }
    float m = s[0];
    #pragma unroll
    for (int tk = 1; tk < TT; ++tk) m = fmaxf(m, s[tk]);
    float den = 0.f;
    #pragma unroll
    for (int tk = 0; tk < TT; ++tk) { s[tk] = expf(s[tk] - m); den += s[tk]; }
    float o0 = 0.f, o1 = 0.f;
    #pragma unroll
    for (int tk = 0; tk < TT; ++tk) {
        const float* v = base + (long)tk * 3072 + 2048 + h * 128;
        o0 += s[tk] * v[lane]; o1 += s[tk] * v[lane + 64];
    }
    const float id = 1.0f / den;
    unsigned short* op = o + ((long)i * TT + tq) * 1024 + h * 128;
    op[lane] = f2bf(o0 * id); op[lane + 64] = f2bf(o1 * id);
}

// ---------------- gating (f32, unchanged) ----------------
__global__ __launch_bounds__(256) void gate_kernel(
    const float* __restrict__ g, const float* __restrict__ gw2,
    const float* __restrict__ gb2, float* __restrict__ wout)
{
    const int b = (int)(((long)blockIdx.x * 256 + threadIdx.x) >> 6);
    const int lane = threadIdx.x & 63;
    float acc[E_] = {};
    const float* row = g + (long)b * 1024;
    for (int d = lane; d < 1024; d += 64) {
        const float x = row[d];
        #pragma unroll
        for (int j = 0; j < E_; ++j) acc[j] += x * gw2[j * 1024 + d];
    }
    #pragma unroll
    for (int j = 0; j < E_; ++j) {
        #pragma unroll
        for (int off = 32; off; off >>= 1) acc[j] += __shfl_xor(acc[j], off);
        acc[j] += gb2[j];
    }
    int i0 = 0; float v0 = acc[0];
    #pragma unroll
    for (int j = 1; j < E_; ++j) if (acc[j] > v0) { v0 = acc[j]; i0 = j; }
    int i1 = -1; float v1 = -1e30f;
    #pragma unroll
    for (int j = 0; j < E_; ++j) if (j != i0 && acc[j] > v1) { v1 = acc[j]; i1 = j; }
    const float p1 = expf(v1 - v0);
    const float den = 1.0f + p1;
    const float g0 = 1.0f / den, g1 = p1 / den;
    if (lane < E_) wout[b * E_ + lane] = (lane == i0) ? g0 : (lane == i1) ? g1 : 0.0f;
}

__global__ __launch_bounds__(256) void build_flat_kernel(
    const float* __restrict__ w, const float* __restrict__ a,
    const float* __restrict__ r, float* __restrict__ flat)
{
    const long e4 = ((long)blockIdx.x * 256 + threadIdx.x) << 2;
    const int b = (int)(e4 / 3072);
    const int cd = (int)(e4 % 3072);
    const int c = cd >> 10, d = cd & 1023;
    const float* src = (c == 0) ? w : (c == 1) ? a : r;
    *(float4*)(flat + e4) = *(const float4*)(src + ((long)b << 10) + d);
}

// seq0[n*B+b][d] = mean_c(trip_c[b][d] + doff[n][c][d])
__global__ __launch_bounds__(256) void seq0_kernel(
    const float* __restrict__ w, const float* __restrict__ a,
    const float* __restrict__ r, const float* __restrict__ doff,
    float* __restrict__ seq0)
{
    const long idx = (long)blockIdx.x * 256 + threadIdx.x;   // BT_*256
    const long i = idx >> 8;
    const int d4 = (int)(idx & 255) << 2;
    const int n = (int)(i / B_), b = (int)(i & (B_ - 1));
    const float4 x = *(const float4*)(w + ((long)b << 10) + d4);
    const float4 y = *(const float4*)(a + ((long)b << 10) + d4);
    const float4 z = *(const float4*)(r + ((long)b << 10) + d4);
    const float4 o0 = *(const float4*)(doff + ((long)(n * 3 + 0) << 10) + d4);
    const float4 o1 = *(const float4*)(doff + ((long)(n * 3 + 1) << 10) + d4);
    const float4 o2 = *(const float4*)(doff + ((long)(n * 3 + 2) << 10) + d4);
    const float c = 1.0f / 3.0f;
    *(float4*)(seq0 + (i << 10) + d4) = make_float4(
        (x.x + y.x + z.x + o0.x + o1.x + o2.x) * c,
        (x.y + y.y + z.y + o0.y + o1.y + o2.y) * c,
        (x.z + y.z + z.z + o0.z + o1.z + o2.z) * c,
        (x.w + y.w + z.w + o0.w + o1.w + o2.w) * c);
}

__global__ __launch_bounds__(256) void mean3_kernel(
    const float* __restrict__ src, float* __restrict__ dst)
{
    const long idx = (long)blockIdx.x * 256 + threadIdx.x;
    const long i = idx >> 8;
    const int d4 = (int)(idx & 255) << 2;
    const float* p = src + i * 3072 + d4;
    const float4 x = *(const float4*)p;
    const float4 y = *(const float4*)(p + 1024);
    const float4 z = *(const float4*)(p + 2048);
    const float c = 1.0f / 3.0f;
    *(float4*)(dst + (i << 10) + d4) = make_float4(
        (x.x + y.x + z.x) * c, (x.y + y.y + z.y) * c,
        (x.z + y.z + z.z) * c, (x.w + y.w + z.w) * c);
}

__global__ __launch_bounds__(256) void build_st_kernel(
    const float* __restrict__ seq, const float* __restrict__ pos_e,
    float* __restrict__ st, int T)
{
    const long idx = (long)blockIdx.x * 256 + threadIdx.x;
    const long row = idx >> 8;
    const int d4 = (int)(idx & 255) << 2;
    const int tau = (int)(row % T);
    const long i = row / T;
    const float4 s = *(const float4*)(seq + (((long)tau * BT_ + i) << 10) + d4);
    const float4 p = *(const float4*)(pos_e + ((long)tau << 10) + d4);
    *(float4*)(st + (row << 10) + d4) = make_float4(s.x + p.x, s.y + p.y, s.z + p.z, s.w + p.w);
}

__global__ __launch_bounds__(256) void combine_kernel(
    const float* __restrict__ tp, const float* __restrict__ wbuf,
    float* __restrict__ out, int e)
{
    const long idx = (long)blockIdx.x * 256 + threadIdx.x;
    const long e4 = idx << 2;
    const long row = e4 / 3072;
    const int cd = (int)(e4 % 3072);
    const int c = cd >> 10, d = cd & 1023;
    const int s = (int)(row / BT_);
    const int i = (int)(row % BT_);
    const int n = i / B_, b = i & (B_ - 1);
    const float wgt = wbuf[b * E_ + e];
    const float4 t = *(const float4*)(tp + e4);
    const long off = ((((long)(n * STEPS_ + s) * 3 + c) * B_ + b) << 10) + d;
    float4 o = make_float4(wgt * t.x, wgt * t.y, wgt * t.z, wgt * t.w);
    if (e != 0) {
        const float4 p = *(const float4*)(out + off);
        o.x += p.x; o.y += p.y; o.z += p.z; o.w += p.w;
    }
    *(float4*)(out + off) = o;
}

// f32 -> bf16 (RNE), vectorized; n4 = count/4
__global__ __launch_bounds__(256) void cvt_bf16_kernel(
    const float* __restrict__ src, unsigned short* __restrict__ dst, long n4)
{
    const long stride = (long)gridDim.x * 256;
    for (long i = (long)blockIdx.x * 256 + threadIdx.x; i < n4; i += stride) {
        const float4 v = *(const float4*)(src + i * 4);
        ushort4 o = make_ushort4(f2bf(v.x), f2bf(v.y), f2bf(v.z), f2bf(v.w));
        *(ushort4*)(dst + i * 4) = o;
    }
}

extern "C" void kernel_launch(void* const* d_in, const int* in_sizes, int n_in,
                              void* d_out, int out_size, void* d_ws, size_t ws_size,
                              hipStream_t stream)
{
    const float* iw   = (const float*)d_in[0];
    const float* ia   = (const float*)d_in[1];
    const float* ir   = (const float*)d_in[2];
    const float* doff = (const float*)d_in[3];
    const float* gw1  = (const float*)d_in[4];
    const float* gb1  = (const float*)d_in[5];
    const float* glnw = (const float*)d_in[6];
    const float* glnb = (const float*)d_in[7];
    const float* gw2  = (const float*)d_in[8];
    const float* gb2  = (const float*)d_in[9];
    const float* pos  = (const float*)d_in[10];
    const float* anw  = (const float*)d_in[11];
    const float* anb  = (const float*)d_in[12];
    const float* inw  = (const float*)d_in[13];
    const float* inb  = (const float*)d_in[14];
    const float* oww  = (const float*)d_in[15];
    const float* owb  = (const float*)d_in[16];
    const float* fnw  = (const float*)d_in[17];
    const float* fnb  = (const float*)d_in[18];
    const float* w1   = (const float*)d_in[19];
    const float* b1   = (const float*)d_in[20];
    const float* w2   = (const float*)d_in[21];
    const float* b2   = (const float*)d_in[22];
    const float* tlnw = (const float*)d_in[23];
    const float* tlnb = (const float*)d_in[24];
    const float* tw1  = (const float*)d_in[25];
    const float* tb1  = (const float*)d_in[26];
    const float* tw2  = (const float*)d_in[27];
    const float* tb2  = (const float*)d_in[28];
    float* out = (float*)d_out;

    // ---- workspace layout (floats) ----
    float* ws    = (float*)d_ws;
    float* wbuf  = ws;                              // 2048
    float* flatb = wbuf + 2048;                     // B_*3072
    float* glin  = flatb + (long)B_ * 3072;         // B_*1024
    float* seq   = glin + (long)B_ * 1024;          // 6*BT_*1024
    float* st    = seq + 6L * BT_ * 1024;           // 5*BT_*1024
    float* qkvb  = st + 5L * BT_ * 1024;            // 5*BT_*3072 (attn qkv + tp out, f32)
    unsigned short* xnB  = (unsigned short*)(qkvb + 5L * BT_ * 3072);   // 5*BT_*1024 bf16
    unsigned short* ffhB = xnB + 5L * BT_ * 1024;                        // 5*BT_*4096 bf16
    unsigned short* wB   = ffhB + 5L * BT_ * 4096;                       // 33554432 bf16
    if (ws_size < 79431680UL * sizeof(float)) return;   // ~318 MB

    // per-expert bf16 weight sub-buffers
    unsigned short* winB = wB;                         // L*3072*1024
    unsigned short* woB  = winB + (long)L_ * 3072 * 1024;  // L*1024*1024
    unsigned short* w1B  = woB  + (long)L_ * 1024 * 1024;  // L*4096*1024
    unsigned short* w2B  = w1B  + (long)L_ * 4096 * 1024;  // L*1024*4096
    unsigned short* t1B  = w2B  + (long)L_ * 1024 * 4096;  // 2048*1024
    unsigned short* t2B  = t1B  + 2048L * 1024;            // 3072*2048

    // ---- gating (pure f32, bit-stable) ----
    build_flat_kernel<<<B_ * 3, 256, 0, stream>>>(iw, ia, ir, flatb);
    gemm_f32<<<dim3(1024 / 64, B_ / 64), 256, 0, stream>>>(
        flatb, gw1, gb1, nullptr, glin, B_, 1024, 3072, 0);
    ln_kernel<1, 0><<<B_, 256, 0, stream>>>(glin, 1024, glnw, glnb, glin);
    gate_kernel<<<B_ / 4, 256, 0, stream>>>(glin, gw2, gb2, wbuf);

    // ---- seq[0] = mean over diversified triplet ----
    seq0_kernel<<<BT_, 256, 0, stream>>>(iw, ia, ir, doff, seq);

    for (int e = 0; e < E_; ++e) {
        // convert this expert's weights to bf16
        cvt_bf16_kernel<<<2048, 256, 0, stream>>>(inw + (long)e * L_ * 3072 * 1024, winB, (long)L_ * 3072 * 1024 / 4);
        cvt_bf16_kernel<<<2048, 256, 0, stream>>>(oww + (long)e * L_ * 1024 * 1024, woB,  (long)L_ * 1024 * 1024 / 4);
        cvt_bf16_kernel<<<2048, 256, 0, stream>>>(w1  + (long)e * L_ * 4096 * 1024, w1B,  (long)L_ * 4096 * 1024 / 4);
        cvt_bf16_kernel<<<2048, 256, 0, stream>>>(w2  + (long)e * L_ * 1024 * 4096, w2B,  (long)L_ * 1024 * 4096 / 4);
        cvt_bf16_kernel<<<2048, 256, 0, stream>>>(tw1 + (long)e * 2048 * 1024,      t1B,  2048L * 1024 / 4);
        cvt_bf16_kernel<<<2048, 256, 0, stream>>>(tw2 + (long)e * 3072 * 2048,      t2B,  3072L * 2048 / 4);

        const float* pos_e = pos + (long)e * 10 * 1024;
        for (int t = 0; t < STEPS_; ++t) {
            const int T = t + 1;
            const int MT = BT_ * T;
            build_st_kernel<<<MT, 256, 0, stream>>>(seq, pos_e, st, T);
            for (int l = 0; l < L_; ++l) {
                const long wi = (long)e * L_ + l;
                ln_kernel<0, 1><<<MT, 256, 0, stream>>>(st, 1024, anw + wi * 1024, anb + wi * 1024, xnB);
                gemm_bf16<0, 0><<<dim3(3072 / 128, MT / 128), 256, 0, stream>>>(
                    xnB, winB + (long)l * 3072 * 1024, inb + wi * 3072, nullptr, qkvb, 3072, 1024);
                switch (T) {
                    case 1: attn_kernel<1><<<BT_ * H_ * 1 / 4, 256, 0, stream>>>(qkvb, xnB); break;
                    case 2: attn_kernel<2><<<BT_ * H_ * 2 / 4, 256, 0, stream>>>(qkvb, xnB); break;
                    case 3: attn_kernel<3><<<BT_ * H_ * 3 / 4, 256, 0, stream>>>(qkvb, xnB); break;
                    case 4: attn_kernel<4><<<BT_ * H_ * 4 / 4, 256, 0, stream>>>(qkvb, xnB); break;
                    case 5: attn_kernel<5><<<BT_ * H_ * 5 / 4, 256, 0, stream>>>(qkvb, xnB); break;
                }
                gemm_bf16<0, 0><<<dim3(1024 / 128, MT / 128), 256, 0, stream>>>(
                    xnB, woB + (long)l * 1024 * 1024, owb + wi * 1024, st, st, 1024, 1024);
                ln_kernel<0, 1><<<MT, 256, 0, stream>>>(st, 1024, fnw + wi * 1024, fnb + wi * 1024, xnB);
                gemm_bf16<1, 1><<<dim3(4096 / 128, MT / 128), 256, 0, stream>>>(
                    xnB, w1B + (long)l * 4096 * 1024, b1 + wi * 4096, nullptr, ffhB, 4096, 1024);
                gemm_bf16<0, 0><<<dim3(1024 / 128, MT / 128), 256, 0, stream>>>(
                    ffhB, w2B + (long)l * 1024 * 4096, b2 + wi * 1024, st, st, 1024, 4096);
            }
            // triplet projection of last token -> next seq entry
            ln_kernel<0, 1><<<BT_, 256, 0, stream>>>(st + (long)t * 1024, (long)T * 1024,
                                                     tlnw + (long)e * 1024, tlnb + (long)e * 1024, xnB);
            gemm_bf16<1, 1><<<dim3(2048 / 128, BT_ / 128), 256, 0, stream>>>(
                xnB, t1B, tb1 + (long)e * 2048, nullptr, ffhB, 2048, 1024);
            gemm_bf16<0, 0><<<dim3(3072 / 128, BT_ / 128), 256, 0, stream>>>(
                ffhB, t2B, tb2 + (long)e * 3072, nullptr, qkvb, 3072, 2048);
            mean3_kernel<<<BT_, 256, 0, stream>>>(qkvb, seq + (long)(t + 1) * BT_ * 1024);
        }
        // final triplet projection over embs = seq[1..5]
        ln_kernel<0, 1><<<STEPS_ * BT_, 256, 0, stream>>>(seq + (long)BT_ * 1024, 1024,
                                                          tlnw + (long)e * 1024, tlnb + (long)e * 1024, xnB);
        gemm_bf16<1, 1><<<dim3(2048 / 128, STEPS_ * BT_ / 128), 256, 0, stream>>>(
            xnB, t1B, tb1 + (long)e * 2048, nullptr, ffhB, 2048, 1024);
        gemm_bf16<0, 0><<<dim3(3072 / 128, STEPS_ * BT_ / 128), 256, 0, stream>>>(
            ffhB, t2B, tb2 + (long)e * 3072, nullptr, qkvb, 3072, 2048);
        combine_kernel<<<STEPS_ * BT_ * 3, 256, 0, stream>>>(qkvb, wbuf, out, e);
    }
}

// Round 3
// 13567.230 us; speedup vs baseline: 5.8077x; 1.2425x over previous
//
#include <hip/hip_runtime.h>
#include <hip/hip_bf16.h>
#include <cstdint>

#define B_  512
#define D_  1024
#define E_  4
#define L_  2
#define FF_ 4096
#define ND_ 3
#define BT_ 1536   // ND_*B_
#define STEPS_ 5
#define H_ 8
#define SLAB_NONE (1 << 30)

typedef __attribute__((ext_vector_type(8))) __bf16 bf16x8;
typedef __attribute__((ext_vector_type(4))) float f32x4;

static __device__ __forceinline__ float gelu_f(float x) {
    return 0.5f * x * (1.0f + erff(x * 0.70710678118654752f));
}

static __device__ __forceinline__ unsigned short f2bf(float x) {
    unsigned u = __builtin_bit_cast(unsigned, x);
    u = (u + 0x7fff + ((u >> 16) & 1)) >> 16;   // RNE
    return (unsigned short)u;
}

static __device__ __forceinline__ void gload16(const void* g, void* l) {
    __builtin_amdgcn_global_load_lds(
        (const __attribute__((address_space(1))) unsigned int*)g,
        (__attribute__((address_space(3))) unsigned int*)l, 16, 0, 0);
}

static __device__ __forceinline__ int pad128(int x) { return (x + 127) & ~127; }

// ---------------- bf16 MFMA GEMM (m97 structure) ----------------
// C[M,N] = act(A[M,K] @ W[N,K]^T + bias) (+R). A,W bf16 (K-contig), bias/R f32.
// Early-exit: block active iff (row0 % slab) < pad128(*cnt3) * mult (cnt3 may be null).
template<int ACT, int OUTBF>
__global__ __launch_bounds__(256) void gemm_bf16(
    const unsigned short* __restrict__ A, const unsigned short* __restrict__ W,
    const float* __restrict__ bias, const float* __restrict__ R,
    void* __restrict__ Cout, int N, int K,
    const int* __restrict__ cnt3, int mult, int slab)
{
    const long row0 = (long)blockIdx.y * 128;
    if (cnt3) {
        if ((int)(row0 % slab) >= pad128(*cnt3) * mult) return;
    }
    __shared__ __align__(16) unsigned short As[128 * 32];
    __shared__ __align__(16) unsigned short Bs[128 * 32];
    const int t = threadIdx.x;
    const int lane = t & 63;
    const int wid = t >> 6;
    const int wr = wid >> 1, wc = wid & 1;
    const long col0 = (long)blockIdx.x * 128;
    const int l15 = lane & 15, l4 = lane >> 4;
    const int ebase = wid << 6;

    f32x4 acc[4][4] = {};

    const int e0 = t, e1 = t + 256;
    const unsigned short* Ag0 = A + (row0 + (e0 >> 2)) * (long)K + (e0 & 3) * 8;
    const unsigned short* Ag1 = A + (row0 + (e1 >> 2)) * (long)K + (e1 & 3) * 8;
    const unsigned short* Wg0 = W + (col0 + (e0 >> 2)) * (long)K + (e0 & 3) * 8;
    const unsigned short* Wg1 = W + (col0 + (e1 >> 2)) * (long)K + (e1 & 3) * 8;
    char* Ad0 = (char*)As + ebase * 16;
    char* Ad1 = (char*)As + (256 + ebase) * 16;
    char* Bd0 = (char*)Bs + ebase * 16;
    char* Bd1 = (char*)Bs + (256 + ebase) * 16;

    for (int k0 = 0; k0 < K; k0 += 32) {
        __syncthreads();
        gload16(Ag0 + k0, Ad0);
        gload16(Ag1 + k0, Ad1);
        gload16(Wg0 + k0, Bd0);
        gload16(Wg1 + k0, Bd1);
        __syncthreads();
        bf16x8 a[4], b[4];
        #pragma unroll
        for (int m = 0; m < 4; ++m)
            a[m] = *(const bf16x8*)((const char*)As + (wr * 64 + m * 16 + l15) * 64 + l4 * 16);
        #pragma unroll
        for (int n = 0; n < 4; ++n)
            b[n] = *(const bf16x8*)((const char*)Bs + (wc * 64 + n * 16 + l15) * 64 + l4 * 16);
        #pragma unroll
        for (int m = 0; m < 4; ++m)
            #pragma unroll
            for (int n = 0; n < 4; ++n)
                acc[m][n] = __builtin_amdgcn_mfma_f32_16x16x32_bf16(a[m], b[n], acc[m][n], 0, 0, 0);
    }

    #pragma unroll
    for (int n = 0; n < 4; ++n) {
        const long col = col0 + wc * 64 + n * 16 + l15;
        const float bn = bias[col];
        #pragma unroll
        for (int m = 0; m < 4; ++m) {
            const long rbase = row0 + wr * 64 + m * 16 + l4 * 4;
            #pragma unroll
            for (int r = 0; r < 4; ++r) {
                float o = acc[m][n][r] + bn;
                if (ACT) o = gelu_f(o);
                const long off = (rbase + r) * (long)N + col;
                if (R) o += R[off];
                if (OUTBF) ((unsigned short*)Cout)[off] = f2bf(o);
                else       ((float*)Cout)[off] = o;
            }
        }
    }
}

// ---------------- f32 GEMM (gating only — bit-stable expert pick) ----------------
__global__ __launch_bounds__(256) void gemm_f32(
    const float* __restrict__ A, const float* __restrict__ W,
    const float* __restrict__ bias, const float* __restrict__ R,
    float* __restrict__ C, int M, int N, int K, int act)
{
    __shared__ float As[16][68];
    __shared__ float Bs[16][68];
    const int tid = threadIdx.x;
    const int tx = tid & 15;
    const int ty = tid >> 4;
    const long row0 = (long)blockIdx.y * 64;
    const long col0 = (long)blockIdx.x * 64;
    const int lr = tid >> 2;
    const int lq = (tid & 3) << 2;
    const float* Ap = A + (row0 + lr) * (long)K + lq;
    const float* Wp = W + (col0 + lr) * (long)K + lq;
    float acc[4][4] = {};
    for (int k0 = 0; k0 < K; k0 += 16) {
        const float4 av = *(const float4*)(Ap + k0);
        const float4 wv = *(const float4*)(Wp + k0);
        __syncthreads();
        As[lq + 0][lr] = av.x; As[lq + 1][lr] = av.y;
        As[lq + 2][lr] = av.z; As[lq + 3][lr] = av.w;
        Bs[lq + 0][lr] = wv.x; Bs[lq + 1][lr] = wv.y;
        Bs[lq + 2][lr] = wv.z; Bs[lq + 3][lr] = wv.w;
        __syncthreads();
        #pragma unroll
        for (int kk = 0; kk < 16; ++kk) {
            const float4 a4 = *(const float4*)&As[kk][ty << 2];
            const float4 b4 = *(const float4*)&Bs[kk][tx << 2];
            const float aa[4] = {a4.x, a4.y, a4.z, a4.w};
            const float bb[4] = {b4.x, b4.y, b4.z, b4.w};
            #pragma unroll
            for (int i = 0; i < 4; ++i)
                #pragma unroll
                for (int j = 0; j < 4; ++j)
                    acc[i][j] = fmaf(aa[i], bb[j], acc[i][j]);
        }
    }
    const float4 bv = *(const float4*)(bias + col0 + (tx << 2));
    const float bb[4] = {bv.x, bv.y, bv.z, bv.w};
    #pragma unroll
    for (int i = 0; i < 4; ++i) {
        const long row = row0 + (ty << 2) + i;
        const long off = row * (long)N + col0 + (tx << 2);
        float o[4];
        #pragma unroll
        for (int j = 0; j < 4; ++j) {
            o[j] = acc[i][j] + bb[j];
            if (act) o[j] = gelu_f(o[j]);
        }
        if (R) {
            const float4 rv = *(const float4*)(R + off);
            o[0] += rv.x; o[1] += rv.y; o[2] += rv.z; o[3] += rv.w;
        }
        *(float4*)(C + off) = make_float4(o[0], o[1], o[2], o[3]);
    }
}

// ---------------- LayerNorm: f32 in, f32 or bf16 out ----------------
template<int ACT, int OUTBF>
__global__ __launch_bounds__(256) void ln_kernel(
    const float* __restrict__ X, long xstride,
    const float* __restrict__ gamma, const float* __restrict__ beta,
    void* __restrict__ Y, const int* __restrict__ cnt3, int mult, int slab)
{
    const long r = blockIdx.x;
    if (cnt3) {
        if ((int)(r % slab) >= pad128(*cnt3) * mult) return;
    }
    const int tid = threadIdx.x;
    __shared__ float red[8];
    const float4 v = *(const float4*)(X + r * xstride + (tid << 2));
    float s = v.x + v.y + v.z + v.w;
    #pragma unroll
    for (int off = 32; off; off >>= 1) s += __shfl_xor(s, off);
    if ((tid & 63) == 0) red[tid >> 6] = s;
    __syncthreads();
    const float mean = (red[0] + red[1] + red[2] + red[3]) * (1.0f / 1024.0f);
    const float dx = v.x - mean, dy = v.y - mean, dz = v.z - mean, dw = v.w - mean;
    float s2 = dx * dx + dy * dy + dz * dz + dw * dw;
    #pragma unroll
    for (int off = 32; off; off >>= 1) s2 += __shfl_xor(s2, off);
    if ((tid & 63) == 0) red[4 + (tid >> 6)] = s2;
    __syncthreads();
    const float var = (red[4] + red[5] + red[6] + red[7]) * (1.0f / 1024.0f);
    const float inv = rsqrtf(var + 1e-5f);
    const float4 g = *(const float4*)(gamma + (tid << 2));
    const float4 b = *(const float4*)(beta + (tid << 2));
    float o0 = dx * inv * g.x + b.x;
    float o1 = dy * inv * g.y + b.y;
    float o2 = dz * inv * g.z + b.z;
    float o3 = dw * inv * g.w + b.w;
    if (ACT) { o0 = gelu_f(o0); o1 = gelu_f(o1); o2 = gelu_f(o2); o3 = gelu_f(o3); }
    if (OUTBF) {
        ushort4 o = make_ushort4(f2bf(o0), f2bf(o1), f2bf(o2), f2bf(o3));
        *(ushort4*)((unsigned short*)Y + (r << 10) + (tid << 2)) = o;
    } else {
        *(float4*)((float*)Y + (r << 10) + (tid << 2)) = make_float4(o0, o1, o2, o3);
    }
}

// ---------------- attention: f32 qkv in, bf16 out ----------------
template<int TT>
__global__ __launch_bounds__(256) void attn_kernel(
    const float* __restrict__ qkv, unsigned short* __restrict__ o,
    const int* __restrict__ cnt3)
{
    const int item = (int)(((long)blockIdx.x * 256 + threadIdx.x) >> 6);
    const int lane = threadIdx.x & 63;
    const int tq = item % TT;
    const int h  = (item / TT) & 7;
    const int i  = item / (TT * 8);
    if (i >= pad128(*cnt3)) return;
    const float* base = qkv + (long)i * TT * 3072;
    const float* q = base + (long)tq * 3072 + h * 128;
    const float q0 = q[lane], q1 = q[lane + 64];
    float s[TT];
    const float scale = 0.088388347648318447f;  // 1/sqrt(128)
    #pragma unroll
    for (int tk = 0; tk < TT; ++tk) {
        const float* k = base + (long)tk * 3072 + 1024 + h * 128;
        float p = q0 * k[lane] + q1 * k[lane + 64];
        #pragma unroll
        for (int off = 32; off; off >>= 1) p += __shfl_xor(p, off);
        s[tk] = p * scale;
    }
    float m = s[0];
    #pragma unroll
    for (int tk = 1; tk < TT; ++tk) m = fmaxf(m, s[tk]);
    float den = 0.f;
    #pragma unroll
    for (int tk = 0; tk < TT; ++tk) { s[tk] = expf(s[tk] - m); den += s[tk]; }
    float o0 = 0.f, o1 = 0.f;
    #pragma unroll
    for (int tk = 0; tk < TT; ++tk) {
        const float* v = base + (long)tk * 3072 + 2048 + h * 128;
        o0 += s[tk] * v[lane]; o1 += s[tk] * v[lane + 64];
    }
    const float id = 1.0f / den;
    unsigned short* op = o + ((long)i * TT + tq) * 1024 + h * 128;
    op[lane] = f2bf(o0 * id); op[lane + 64] = f2bf(o1 * id);
}

// ---------------- gating ----------------
__global__ __launch_bounds__(256) void gate_kernel(
    const float* __restrict__ g, const float* __restrict__ gw2,
    const float* __restrict__ gb2, float* __restrict__ wout)
{
    const int b = (int)(((long)blockIdx.x * 256 + threadIdx.x) >> 6);
    const int lane = threadIdx.x & 63;
    float acc[E_] = {};
    const float* row = g + (long)b * 1024;
    for (int d = lane; d < 1024; d += 64) {
        const float x = row[d];
        #pragma unroll
        for (int j = 0; j < E_; ++j) acc[j] += x * gw2[j * 1024 + d];
    }
    #pragma unroll
    for (int j = 0; j < E_; ++j) {
        #pragma unroll
        for (int off = 32; off; off >>= 1) acc[j] += __shfl_xor(acc[j], off);
        acc[j] += gb2[j];
    }
    int i0 = 0; float v0 = acc[0];
    #pragma unroll
    for (int j = 1; j < E_; ++j) if (acc[j] > v0) { v0 = acc[j]; i0 = j; }
    int i1 = -1; float v1 = -1e30f;
    #pragma unroll
    for (int j = 0; j < E_; ++j) if (j != i0 && acc[j] > v1) { v1 = acc[j]; i1 = j; }
    const float p1 = expf(v1 - v0);
    const float den = 1.0f + p1;
    const float g0 = 1.0f / den, g1 = p1 / den;
    if (lane < E_) wout[b * E_ + lane] = (lane == i0) ? g0 : (lane == i1) ? g1 : 0.0f;
}

// per-expert compacted index list: idx[3j+n] = n*512 + b for j-th selected b (ascending)
__global__ __launch_bounds__(64) void build_idx_kernel(
    const float* __restrict__ wbuf, int* __restrict__ idx, int* __restrict__ cnt3)
{
    const int e = blockIdx.x;
    const int lane = threadIdx.x;
    int* my = idx + e * BT_;
    int base = 0;
    for (int chunk = 0; chunk < 8; ++chunk) {
        const int b = chunk * 64 + lane;
        const bool sel = wbuf[b * E_ + e] > 0.0f;
        const unsigned long long mask = __ballot(sel);
        const int pos = base + (int)__popcll(mask & ((1ull << lane) - 1ull));
        if (sel) {
            my[3 * pos + 0] = 0 * 512 + b;
            my[3 * pos + 1] = 1 * 512 + b;
            my[3 * pos + 2] = 2 * 512 + b;
        }
        base += (int)__popcll(mask);
    }
    if (lane == 0) cnt3[e] = 3 * base;
    for (int r = 3 * base + lane; r < BT_; r += 64) my[r] = -1;
}

// gather seq0 (compacted): row r -> mean over triplet + offsets; zero-fill padding
__global__ __launch_bounds__(256) void seq0_gather_kernel(
    const float* __restrict__ w, const float* __restrict__ a,
    const float* __restrict__ rr, const float* __restrict__ doff,
    const int* __restrict__ idx, const int* __restrict__ cnt3,
    float* __restrict__ seq0)
{
    const int r = blockIdx.x;     // [0, 1536)
    const int d4 = threadIdx.x << 2;
    float4 res = make_float4(0.f, 0.f, 0.f, 0.f);
    if (r < *cnt3) {
        const int v = idx[r];
        const int n = v >> 9, b = v & 511;
        const float4 x = *(const float4*)(w + ((long)b << 10) + d4);
        const float4 y = *(const float4*)(a + ((long)b << 10) + d4);
        const float4 z = *(const float4*)(rr + ((long)b << 10) + d4);
        const float4 o0 = *(const float4*)(doff + ((long)(n * 3 + 0) << 10) + d4);
        const float4 o1 = *(const float4*)(doff + ((long)(n * 3 + 1) << 10) + d4);
        const float4 o2 = *(const float4*)(doff + ((long)(n * 3 + 2) << 10) + d4);
        const float c = 1.0f / 3.0f;
        res = make_float4(
            (x.x + y.x + z.x + o0.x + o1.x + o2.x) * c,
            (x.y + y.y + z.y + o0.y + o1.y + o2.y) * c,
            (x.z + y.z + z.z + o0.z + o1.z + o2.z) * c,
            (x.w + y.w + z.w + o0.w + o1.w + o2.w) * c);
    }
    *(float4*)(seq0 + ((long)r << 10) + d4) = res;
}

__global__ __launch_bounds__(256) void build_flat_kernel(
    const float* __restrict__ w, const float* __restrict__ a,
    const float* __restrict__ r, float* __restrict__ flat)
{
    const long e4 = ((long)blockIdx.x * 256 + threadIdx.x) << 2;
    const int b = (int)(e4 / 3072);
    const int cd = (int)(e4 % 3072);
    const int c = cd >> 10, d = cd & 1023;
    const float* src = (c == 0) ? w : (c == 1) ? a : r;
    *(float4*)(flat + e4) = *(const float4*)(src + ((long)b << 10) + d);
}

// mean over 3 chunks of 1024, one block per row, early-exit at pad128(cnt3)
__global__ __launch_bounds__(256) void mean3_kernel(
    const float* __restrict__ src, float* __restrict__ dst,
    const int* __restrict__ cnt3)
{
    const int r = blockIdx.x;
    if (r >= pad128(*cnt3)) return;
    const int d4 = threadIdx.x << 2;
    const float* p = src + (long)r * 3072 + d4;
    const float4 x = *(const float4*)p;
    const float4 y = *(const float4*)(p + 1024);
    const float4 z = *(const float4*)(p + 2048);
    const float c = 1.0f / 3.0f;
    *(float4*)(dst + ((long)r << 10) + d4) = make_float4(
        (x.x + y.x + z.x) * c, (x.y + y.y + z.y) * c,
        (x.z + y.z + z.z) * c, (x.w + y.w + z.w) * c);
}

__global__ __launch_bounds__(256) void build_st_kernel(
    const float* __restrict__ seq, const float* __restrict__ pos_e,
    float* __restrict__ st, int T, const int* __restrict__ cnt3)
{
    const int row = blockIdx.x;           // [0, 1536*T)
    const int r = row / T;
    if (r >= pad128(*cnt3)) return;
    const int tau = row - r * T;
    const int d4 = threadIdx.x << 2;
    const float4 s = *(const float4*)(seq + (((long)tau * BT_ + r) << 10) + d4);
    const float4 p = *(const float4*)(pos_e + ((long)tau << 10) + d4);
    *(float4*)(st + ((long)row << 10) + d4) = make_float4(s.x + p.x, s.y + p.y, s.z + p.z, s.w + p.w);
}

// out[n,s,c,b,:] += w[b][e] * tp[s*1536 + r, c*1024 + :]
__global__ __launch_bounds__(256) void scatter_combine_kernel(
    const float* __restrict__ tp, const float* __restrict__ wbuf,
    const int* __restrict__ idx, const int* __restrict__ cnt3,
    float* __restrict__ out, int e)
{
    const int s = blockIdx.x / BT_;
    const int r = blockIdx.x - s * BT_;
    if (r >= *cnt3) return;
    const int v = idx[r];
    const int n = v >> 9, b = v & 511;
    const float wgt = wbuf[b * E_ + e];
    const int d4 = threadIdx.x << 2;
    const float* trow = tp + (long)blockIdx.x * 3072;
    #pragma unroll
    for (int c = 0; c < 3; ++c) {
        const float4 t = *(const float4*)(trow + c * 1024 + d4);
        float* op = out + (((long)((n * STEPS_ + s) * 3 + c) * B_ + b) << 10) + d4;
        float4 o = *(const float4*)op;
        o.x += wgt * t.x; o.y += wgt * t.y; o.z += wgt * t.z; o.w += wgt * t.w;
        *(float4*)op = o;
    }
}

__global__ __launch_bounds__(256) void zero_kernel(float* __restrict__ p, long n4)
{
    const long stride = (long)gridDim.x * 256;
    for (long i = (long)blockIdx.x * 256 + threadIdx.x; i < n4; i += stride)
        *(float4*)(p + i * 4) = make_float4(0.f, 0.f, 0.f, 0.f);
}

__global__ __launch_bounds__(256) void cvt_bf16_kernel(
    const float* __restrict__ src, unsigned short* __restrict__ dst, long n4)
{
    const long stride = (long)gridDim.x * 256;
    for (long i = (long)blockIdx.x * 256 + threadIdx.x; i < n4; i += stride) {
        const float4 v = *(const float4*)(src + i * 4);
        ushort4 o = make_ushort4(f2bf(v.x), f2bf(v.y), f2bf(v.z), f2bf(v.w));
        *(ushort4*)(dst + i * 4) = o;
    }
}

extern "C" void kernel_launch(void* const* d_in, const int* in_sizes, int n_in,
                              void* d_out, int out_size, void* d_ws, size_t ws_size,
                              hipStream_t stream)
{
    const float* iw   = (const float*)d_in[0];
    const float* ia   = (const float*)d_in[1];
    const float* ir   = (const float*)d_in[2];
    const float* doff = (const float*)d_in[3];
    const float* gw1  = (const float*)d_in[4];
    const float* gb1  = (const float*)d_in[5];
    const float* glnw = (const float*)d_in[6];
    const float* glnb = (const float*)d_in[7];
    const float* gw2  = (const float*)d_in[8];
    const float* gb2  = (const float*)d_in[9];
    const float* pos  = (const float*)d_in[10];
    const float* anw  = (const float*)d_in[11];
    const float* anb  = (const float*)d_in[12];
    const float* inw  = (const float*)d_in[13];
    const float* inb  = (const float*)d_in[14];
    const float* oww  = (const float*)d_in[15];
    const float* owb  = (const float*)d_in[16];
    const float* fnw  = (const float*)d_in[17];
    const float* fnb  = (const float*)d_in[18];
    const float* w1   = (const float*)d_in[19];
    const float* b1   = (const float*)d_in[20];
    const float* w2   = (const float*)d_in[21];
    const float* b2   = (const float*)d_in[22];
    const float* tlnw = (const float*)d_in[23];
    const float* tlnb = (const float*)d_in[24];
    const float* tw1  = (const float*)d_in[25];
    const float* tb1  = (const float*)d_in[26];
    const float* tw2  = (const float*)d_in[27];
    const float* tb2  = (const float*)d_in[28];
    float* out = (float*)d_out;

    // ---- workspace layout ----
    float* ws    = (float*)d_ws;
    float* wbuf  = ws;                              // 2048
    int*   cnt3  = (int*)(wbuf + 2048);             // 16
    int*   idxb  = cnt3 + 16;                       // 4*1536
    float* flatb = (float*)(idxb + 4 * BT_);        // B_*3072
    float* glin  = flatb + (long)B_ * 3072;         // B_*1024
    float* seq   = glin + (long)B_ * 1024;          // 6*BT_*1024
    float* st    = seq + 6L * BT_ * 1024;           // 5*BT_*1024
    float* qkvb  = st + 5L * BT_ * 1024;            // 5*BT_*3072
    unsigned short* xnB  = (unsigned short*)(qkvb + 5L * BT_ * 3072);   // 5*BT_*1024 bf16
    unsigned short* ffhB = xnB + 5L * BT_ * 1024;                        // 5*BT_*4096 bf16
    unsigned short* wB   = ffhB + 5L * BT_ * 4096;                       // 33554432 bf16
    if (ws_size < 79437900UL * sizeof(float)) return;

    unsigned short* winB = wB;
    unsigned short* woB  = winB + (long)L_ * 3072 * 1024;
    unsigned short* w1B  = woB  + (long)L_ * 1024 * 1024;
    unsigned short* w2B  = w1B  + (long)L_ * 4096 * 1024;
    unsigned short* t1B  = w2B  + (long)L_ * 1024 * 4096;
    unsigned short* t2B  = t1B  + 2048L * 1024;

    // ---- gating (pure f32, bit-stable) ----
    build_flat_kernel<<<B_ * 3, 256, 0, stream>>>(iw, ia, ir, flatb);
    gemm_f32<<<dim3(1024 / 64, B_ / 64), 256, 0, stream>>>(
        flatb, gw1, gb1, nullptr, glin, B_, 1024, 3072, 0);
    ln_kernel<1, 0><<<B_, 256, 0, stream>>>(glin, 1024, glnw, glnb, glin, nullptr, 1, SLAB_NONE);
    gate_kernel<<<B_ / 4, 256, 0, stream>>>(glin, gw2, gb2, wbuf);
    build_idx_kernel<<<E_, 64, 0, stream>>>(wbuf, idxb, cnt3);

    // ---- zero output (experts scatter-accumulate) ----
    zero_kernel<<<2048, 256, 0, stream>>>(out, (long)ND_ * STEPS_ * 3 * B_ * 1024 / 4);

    for (int e = 0; e < E_; ++e) {
        const int* ce = cnt3 + e;
        const int* ie = idxb + e * BT_;

        cvt_bf16_kernel<<<2048, 256, 0, stream>>>(inw + (long)e * L_ * 3072 * 1024, winB, (long)L_ * 3072 * 1024 / 4);
        cvt_bf16_kernel<<<2048, 256, 0, stream>>>(oww + (long)e * L_ * 1024 * 1024, woB,  (long)L_ * 1024 * 1024 / 4);
        cvt_bf16_kernel<<<2048, 256, 0, stream>>>(w1  + (long)e * L_ * 4096 * 1024, w1B,  (long)L_ * 4096 * 1024 / 4);
        cvt_bf16_kernel<<<2048, 256, 0, stream>>>(w2  + (long)e * L_ * 1024 * 4096, w2B,  (long)L_ * 1024 * 4096 / 4);
        cvt_bf16_kernel<<<2048, 256, 0, stream>>>(tw1 + (long)e * 2048 * 1024,      t1B,  2048L * 1024 / 4);
        cvt_bf16_kernel<<<2048, 256, 0, stream>>>(tw2 + (long)e * 3072 * 2048,      t2B,  3072L * 2048 / 4);

        seq0_gather_kernel<<<BT_, 256, 0, stream>>>(iw, ia, ir, doff, ie, ce, seq);

        const float* pos_e = pos + (long)e * 10 * 1024;
        for (int t = 0; t < STEPS_; ++t) {
            const int T = t + 1;
            const int MT = BT_ * T;   // worst-case grid; blocks early-exit at pad*T
            build_st_kernel<<<MT, 256, 0, stream>>>(seq, pos_e, st, T, ce);
            for (int l = 0; l < L_; ++l) {
                const long wi = (long)e * L_ + l;
                ln_kernel<0, 1><<<MT, 256, 0, stream>>>(st, 1024, anw + wi * 1024, anb + wi * 1024, xnB, ce, T, SLAB_NONE);
                gemm_bf16<0, 0><<<dim3(3072 / 128, MT / 128), 256, 0, stream>>>(
                    xnB, winB + (long)l * 3072 * 1024, inb + wi * 3072, nullptr, qkvb, 3072, 1024, ce, T, SLAB_NONE);
                switch (T) {
                    case 1: attn_kernel<1><<<BT_ * H_ * 1 / 4, 256, 0, stream>>>(qkvb, xnB, ce); break;
                    case 2: attn_kernel<2><<<BT_ * H_ * 2 / 4, 256, 0, stream>>>(qkvb, xnB, ce); break;
                    case 3: attn_kernel<3><<<BT_ * H_ * 3 / 4, 256, 0, stream>>>(qkvb, xnB, ce); break;
                    case 4: attn_kernel<4><<<BT_ * H_ * 4 / 4, 256, 0, stream>>>(qkvb, xnB, ce); break;
                    case 5: attn_kernel<5><<<BT_ * H_ * 5 / 4, 256, 0, stream>>>(qkvb, xnB, ce); break;
                }
                gemm_bf16<0, 0><<<dim3(1024 / 128, MT / 128), 256, 0, stream>>>(
                    xnB, woB + (long)l * 1024 * 1024, owb + wi * 1024, st, st, 1024, 1024, ce, T, SLAB_NONE);
                ln_kernel<0, 1><<<MT, 256, 0, stream>>>(st, 1024, fnw + wi * 1024, fnb + wi * 1024, xnB, ce, T, SLAB_NONE);
                gemm_bf16<1, 1><<<dim3(4096 / 128, MT / 128), 256, 0, stream>>>(
                    xnB, w1B + (long)l * 4096 * 1024, b1 + wi * 4096, nullptr, ffhB, 4096, 1024, ce, T, SLAB_NONE);
                gemm_bf16<0, 0><<<dim3(1024 / 128, MT / 128), 256, 0, stream>>>(
                    ffhB, w2B + (long)l * 1024 * 4096, b2 + wi * 1024, st, st, 1024, 4096, ce, T, SLAB_NONE);
            }
            // triplet projection of last token -> next seq entry
            ln_kernel<0, 1><<<BT_, 256, 0, stream>>>(st + (long)t * 1024, (long)T * 1024,
                                                     tlnw + (long)e * 1024, tlnb + (long)e * 1024, xnB, ce, 1, SLAB_NONE);
            gemm_bf16<1, 1><<<dim3(2048 / 128, BT_ / 128), 256, 0, stream>>>(
                xnB, t1B, tb1 + (long)e * 2048, nullptr, ffhB, 2048, 1024, ce, 1, SLAB_NONE);
            gemm_bf16<0, 0><<<dim3(3072 / 128, BT_ / 128), 256, 0, stream>>>(
                ffhB, t2B, tb2 + (long)e * 3072, nullptr, qkvb, 3072, 2048, ce, 1, SLAB_NONE);
            mean3_kernel<<<BT_, 256, 0, stream>>>(qkvb, seq + (long)(t + 1) * BT_ * 1024, ce);
        }
        // final triplet projection over embs = seq[1..5] (5 slabs of 1536 rows)
        ln_kernel<0, 1><<<STEPS_ * BT_, 256, 0, stream>>>(seq + (long)BT_ * 1024, 1024,
                                                          tlnw + (long)e * 1024, tlnb + (long)e * 1024, xnB, ce, 1, BT_);
        gemm_bf16<1, 1><<<dim3(2048 / 128, STEPS_ * BT_ / 128), 256, 0, stream>>>(
            xnB, t1B, tb1 + (long)e * 2048, nullptr, ffhB, 2048, 1024, ce, 1, BT_);
        gemm_bf16<0, 0><<<dim3(3072 / 128, STEPS_ * BT_ / 128), 256, 0, stream>>>(
            ffhB, t2B, tb2 + (long)e * 3072, nullptr, qkvb, 3072, 2048, ce, 1, BT_);
        scatter_combine_kernel<<<STEPS_ * BT_, 256, 0, stream>>>(qkvb, wbuf, ie, ce, out, e);
    }
}